// Round 10
// baseline (1228.484 us; speedup 1.0000x reference)
//
#include <hip/hip_runtime.h>
#include <hip/hip_bf16.h>

typedef unsigned char uchar_t;
typedef __attribute__((ext_vector_type(4)))  float f32x4;
typedef __attribute__((ext_vector_type(16))) float f32x16;

#define B_SZ 8192
#define D_FT 784
#define N_KT 13
#define PLANE_U32 131072   // 8192 rows * 16 uints (64 B) per plane
#define PLANE_B   524288   // plane stride in bytes
#define THRESH 0.9f
#define N_REP 8            // MEASUREMENT: repeat sparse-gram body 8x
#define Z_REP 8            // MEASUREMENT: repeat zero-fill 8x

#define GLOBAL_AS(p) ((const __attribute__((address_space(1))) void*)(p))
#define LDS_AS(p)    ((__attribute__((address_space(3))) void*)(p))

// R15 MEASUREMENT A: zero-fill with PLAIN f32x4 stores (NT dropped -- NT
// 16B stores bypassing L2 cause partial-line RMW at HBM: R7's FETCH=153MB
// ~ WRITE/2 signature). 8 internal reps force this kernel into the top-5
// for a direct BW reading. If plain stores hit ~6 TB/s, Z_true ~ 45 us.
__global__ __launch_bounds__(256) void zero_adj_kernel(float* __restrict__ adj)
{
    const size_t n4 = (size_t)B_SZ * B_SZ / 4;
    f32x4 z = {0.f, 0.f, 0.f, 0.f};
    f32x4* p = (f32x4*)adj;
    #pragma unroll 1
    for (int rep = 0; rep < Z_REP; ++rep) {
        for (size_t i = (size_t)blockIdx.x * 256 + threadIdx.x; i < n4;
             i += (size_t)gridDim.x * 256)
            p[i] = z;
    }
}

// Wave-per-row preproc: 2048 blocks x 4 waves; wave w handles row blockIdx*4+w.
// conv 2x2/s2 + bias -> 4x4 unitary -> qf (LDS, fp32), row norm -> qn fp8 e4m3.
// qn is K-PLANE-BLOCKED: qn[kt][row][64 B] (13 planes of 512 KB).
__global__ __launch_bounds__(256) void preproc_kernel(
    const float* __restrict__ x, const float* __restrict__ conv_w,
    const float* __restrict__ conv_b, const float* __restrict__ unitary,
    const float* __restrict__ lin_w, const float* __restrict__ lin_b,
    float* __restrict__ log_probs, uchar_t* __restrict__ qn)
{
    __shared__ float xr[4][784];
    __shared__ float qf[4][784];

    const int t = threadIdx.x, lane = t & 63, wave = t >> 6;
    const int b = blockIdx.x * 4 + wave;
    float* xw = xr[wave];
    float* qw = qf[wave];

    const float4* xsrc = (const float4*)(x + (size_t)b * 784);
    #pragma unroll
    for (int i = lane; i < 196; i += 64) ((float4*)xw)[i] = xsrc[i];
    __syncthreads();

    float sumsq = 0.f;
    for (int g = lane; g < 196; g += 64) {
        const int c = g / 49, p = g % 49;
        const float w00 = conv_w[c*4+0], w01 = conv_w[c*4+1];
        const float w10 = conv_w[c*4+2], w11 = conv_w[c*4+3];
        const float bcv = conv_b[c];
        float feat[4];
        #pragma unroll
        for (int j = 0; j < 4; ++j) {
            const int s = 4*p + j;
            const int h = s / 14, wq = s % 14;
            const float* px = &xw[(2*h)*28 + 2*wq];
            feat[j] = bcv + w00*px[0] + w01*px[1] + w10*px[28] + w11*px[29];
        }
        #pragma unroll
        for (int w = 0; w < 4; ++w) {
            float v = unitary[w*4+0]*feat[0] + unitary[w*4+1]*feat[1]
                    + unitary[w*4+2]*feat[2] + unitary[w*4+3]*feat[3];
            qw[4*g + w] = v;
            sumsq += v * v;
        }
    }
    __syncthreads();

    #pragma unroll
    for (int off = 1; off < 64; off <<= 1) sumsq += __shfl_xor(sumsq, off, 64);
    const float inv = 1.0f / (sqrtf(sumsq) + 1e-12f);

    unsigned int* qbase = (unsigned int*)qn;
    for (int i = lane; i < 208; i += 64) {
        unsigned int o = 0u;
        if (i < 196) {
            const float v0 = qw[4*i+0] * inv, v1 = qw[4*i+1] * inv;
            const float v2 = qw[4*i+2] * inv, v3 = qw[4*i+3] * inv;
            int lo = __builtin_amdgcn_cvt_pk_fp8_f32(v0, v1, 0, 0);
            o = (unsigned int)__builtin_amdgcn_cvt_pk_fp8_f32(v2, v3, lo, 1);
        }
        qbase[(size_t)(i >> 4) * PLANE_U32 + (size_t)b * 16 + (i & 15)] = o;
    }

    float acc[10];
    #pragma unroll
    for (int cl = 0; cl < 10; ++cl) acc[cl] = 0.f;
    for (int k = lane; k < 784; k += 64) {
        const float v = qw[k];
        #pragma unroll
        for (int cl = 0; cl < 10; ++cl) acc[cl] += v * lin_w[cl*784 + k];
    }
    #pragma unroll
    for (int cl = 0; cl < 10; ++cl) {
        #pragma unroll
        for (int off = 1; off < 64; off <<= 1)
            acc[cl] += __shfl_xor(acc[cl], off, 64);
        acc[cl] += lin_b[cl];
    }
    if (lane == 0) {
        float mx = -1e30f;
        #pragma unroll
        for (int cl = 0; cl < 10; ++cl) mx = fmaxf(mx, acc[cl]);
        float se = 0.f;
        #pragma unroll
        for (int cl = 0; cl < 10; ++cl) se += expf(acc[cl] - mx);
        const float lse = mx + logf(se);
        #pragma unroll
        for (int cl = 0; cl < 10; ++cl)
            log_probs[(size_t)b*10 + cl] = acc[cl] - lse;
    }
}

// R15 MEASUREMENT B: R14's SPARSE gram repeated N_REP=8x in one dispatch
// for a direct duration + counter reading of the store-free K-loop.
// Discriminates: model A (loop intrinsically ~150 us -> rep ~1170 us, low
// MfmaUtil, tiny FETCH/WRITE => latency/sync-bound, traffic was never the
// cause) vs model B (loop ~25 us -> ~200 us, MfmaUtil high => R8/R9's
// regression was the fills).
// vs R12's repeat: added a REP-START BARRIER -- all waves finish rep r-1's
// kt=12 ds_reads (data-dep before their epilogue) before any wave's rep-r
// STAGE overwrites buf 0 (kt=12 uses p=0). Removes R12's latent race.
// Per-rep vmcnt: rep-start queue young->old = [S1 4][S0 4][epi N];
// kt=0 vmcnt(4) retires S0+epi; kt=1..11 vmcnt(4); kt=12 vmcnt(0).
__global__ __launch_bounds__(512, 2) void gram_kernel(
    const uchar_t* __restrict__ qn, float* __restrict__ adj)
{
    // XCD-bijective swizzle: 528 = 8 * 66.
    const int t0 = blockIdx.x;
    int tl = (t0 & 7) * 66 + (t0 >> 3);
    int br = (int)((65.0 - sqrt(4225.0 - 8.0 * (double)tl)) * 0.5);
    while ((br + 1) * (65 - (br + 1)) / 2 <= tl) ++br;
    while (br * (65 - br) / 2 > tl) --br;
    const int bc = br + (tl - br * (65 - br) / 2);

    __shared__ uchar_t ldsA[3][16384] __attribute__((aligned(16)));  // 48 KB
    __shared__ uchar_t ldsB[3][16384] __attribute__((aligned(16)));  // 48 KB

    const int t = threadIdx.x;
    const int lane = t & 63, wave = t >> 6;       // 8 waves
    const int wrow = wave >> 1, wcol = wave & 1;  // 4x2 -> 64x128 per wave
    const int l32 = lane & 31, half = lane >> 5;

    const bool offdiag = (br != bc);
    const int br256 = br * 256, bc256 = bc * 256;

    const int srow = lane & 15, sck = (lane >> 4) * 16;
    const uchar_t* gA0 = qn + (size_t)(br256 + wave*16       + srow) * 64 + sck;
    const uchar_t* gA1 = qn + (size_t)(br256 + (wave+8)*16   + srow) * 64 + sck;
    const uchar_t* gB0 = qn + (size_t)(bc256 + wave*16       + srow) * 64 + sck;
    const uchar_t* gB1 = qn + (size_t)(bc256 + (wave+8)*16   + srow) * 64 + sck;
    const int ld0 = wave * 1024, ld1 = (wave + 8) * 1024;

    #define STAGE(p, koff) do {                                                            \
        __builtin_amdgcn_global_load_lds(GLOBAL_AS(gA0 + (koff)), LDS_AS(&ldsA[p][ld0]), 16, 0, 0); \
        __builtin_amdgcn_global_load_lds(GLOBAL_AS(gA1 + (koff)), LDS_AS(&ldsA[p][ld1]), 16, 0, 0); \
        __builtin_amdgcn_global_load_lds(GLOBAL_AS(gB0 + (koff)), LDS_AS(&ldsB[p][ld0]), 16, 0, 0); \
        __builtin_amdgcn_global_load_lds(GLOBAL_AS(gB1 + (koff)), LDS_AS(&ldsB[p][ld1]), 16, 0, 0); \
    } while (0)

    int aoff[2], boff[4];
    #pragma unroll
    for (int mi = 0; mi < 2; ++mi) {
        const int r = wrow*64 + mi*32 + l32;
        aoff[mi] = (r >> 4)*1024 + (r & 15)*16 + half*8;
    }
    #pragma unroll
    for (int ni = 0; ni < 4; ++ni) {
        const int c = wcol*128 + ni*32 + l32;
        boff[ni] = (c >> 4)*1024 + (c & 15)*16 + half*8;
    }

    #pragma unroll 1
    for (int rep = 0; rep < N_REP; ++rep) {
        // rep-start barrier: prior rep's ds_reads (all complete before each
        // wave's epilogue) are globally done before STAGE overwrites buf 0.
        __builtin_amdgcn_s_barrier();
        asm volatile("" ::: "memory");

        f32x16 acc[2][4] = {};
        STAGE(0, 0);
        STAGE(1, PLANE_B);

        #pragma unroll
        for (int kt = 0; kt < N_KT; ++kt) {
            const int p = kt % 3, p2 = (kt + 2) % 3;

            asm volatile("" ::: "memory");
            if (kt == N_KT - 1) __builtin_amdgcn_s_waitcnt(0xF70);  // vmcnt(0)
            else                __builtin_amdgcn_s_waitcnt(0xF74);  // vmcnt(4)
            __builtin_amdgcn_s_barrier();    // tile kt in LDS; buf kt-1 dead
            asm volatile("" ::: "memory");

            if (kt + 2 < N_KT) STAGE(p2, (size_t)(kt + 2) * PLANE_B);
            asm volatile("" ::: "memory");

            #pragma unroll
            for (int s = 0; s < 4; ++s) {
                long a0 = *(const long*)&ldsA[p][aoff[0] + s*256];
                long a1 = *(const long*)&ldsA[p][aoff[1] + s*256];
                long b0 = *(const long*)&ldsB[p][boff[0] + s*256];
                long b1 = *(const long*)&ldsB[p][boff[1] + s*256];
                long b2 = *(const long*)&ldsB[p][boff[2] + s*256];
                long b3 = *(const long*)&ldsB[p][boff[3] + s*256];
                acc[0][0] = __builtin_amdgcn_mfma_f32_32x32x16_fp8_fp8(a0, b0, acc[0][0], 0, 0, 0);
                acc[1][0] = __builtin_amdgcn_mfma_f32_32x32x16_fp8_fp8(a1, b0, acc[1][0], 0, 0, 0);
                acc[0][1] = __builtin_amdgcn_mfma_f32_32x32x16_fp8_fp8(a0, b1, acc[0][1], 0, 0, 0);
                acc[1][1] = __builtin_amdgcn_mfma_f32_32x32x16_fp8_fp8(a1, b1, acc[1][1], 0, 0, 0);
                acc[0][2] = __builtin_amdgcn_mfma_f32_32x32x16_fp8_fp8(a0, b2, acc[0][2], 0, 0, 0);
                acc[1][2] = __builtin_amdgcn_mfma_f32_32x32x16_fp8_fp8(a1, b2, acc[1][2], 0, 0, 0);
                acc[0][3] = __builtin_amdgcn_mfma_f32_32x32x16_fp8_fp8(a0, b3, acc[0][3], 0, 0, 0);
                acc[1][3] = __builtin_amdgcn_mfma_f32_32x32x16_fp8_fp8(a1, b3, acc[1][3], 0, 0, 0);
            }
        }

        // Sparse epilogue: zeros pre-written by zero_adj (stream-ordered);
        // only store reg-quads containing a 1 (__any guard). Idempotent
        // across reps (never writes zeros).
        #pragma unroll
        for (int mi = 0; mi < 2; ++mi) {
            const int rbase = br256 + wrow*64 + mi*32 + 4*half;
            #pragma unroll
            for (int ni = 0; ni < 4; ++ni) {
                const int gc = bc256 + wcol*128 + ni*32 + l32;
                const f32x16 v = acc[mi][ni];
                #pragma unroll
                for (int q = 0; q < 4; ++q) {
                    const int gr0 = rbase + 8*q;
                    float o[4];
                    bool h = false;
                    #pragma unroll
                    for (int r = 0; r < 4; ++r) {
                        const float val = v[4*q + r];
                        o[r] = (val*val >= THRESH && (gr0 + r) != gc) ? 1.0f : 0.0f;
                        h = h || (o[r] != 0.0f);
                    }
                    if (__any(h)) {
                        #pragma unroll
                        for (int r = 0; r < 4; ++r)
                            adj[(size_t)(gr0 + r) * B_SZ + gc] = o[r];
                        if (offdiag)
                            *(float4*)&adj[(size_t)gc * B_SZ + gr0] =
                                make_float4(o[0], o[1], o[2], o[3]);
                    }
                }
            }
        }
    }
    #undef STAGE
}

extern "C" void kernel_launch(void* const* d_in, const int* in_sizes, int n_in,
                              void* d_out, int out_size, void* d_ws, size_t ws_size,
                              hipStream_t stream) {
    const float* x       = (const float*)d_in[0];
    const float* conv_w  = (const float*)d_in[1];
    const float* conv_b  = (const float*)d_in[2];
    const float* unitary = (const float*)d_in[3];
    const float* lin_w   = (const float*)d_in[4];
    const float* lin_b   = (const float*)d_in[5];

    float* log_probs = (float*)d_out;
    float* adj       = (float*)d_out + (size_t)B_SZ * 10;
    uchar_t* qn      = (uchar_t*)d_ws;   // 13 planes x [8192][64 B] fp8 e4m3

    zero_adj_kernel<<<4096, 256, 0, stream>>>(adj);
    preproc_kernel<<<B_SZ / 4, 256, 0, stream>>>(x, conv_w, conv_b, unitary,
                                                 lin_w, lin_b, log_probs, qn);
    gram_kernel<<<528, 512, 0, stream>>>(qn, adj);
}

// Round 11
// 993.501 us; speedup vs baseline: 1.2365x; 1.2365x over previous
//
#include <hip/hip_runtime.h>
#include <hip/hip_bf16.h>

typedef unsigned char uchar_t;
typedef __attribute__((ext_vector_type(4)))  float f32x4;
typedef __attribute__((ext_vector_type(16))) float f32x16;

#define B_SZ 8192
#define D_FT 784
#define N_KT 13
#define PLANE_U32 131072   // 8192 rows * 16 uints (64 B) per plane
#define PLANE_B   524288   // plane stride in bytes
#define THRESH 0.9f

#define GLOBAL_AS(p) ((const __attribute__((address_space(1))) void*)(p))
#define LDS_AS(p)    ((__attribute__((address_space(3))) void*)(p))

// R16: zero-fill with PLAIN f32x4 stores. R10 decomposition: plain-store
// fill = ~35 us (~6-7 TB/s). NT 16-B stores were 2.5x slower (partial-line
// RMW at HBM: R7's FETCH ~ WRITE/2 signature). Do NOT re-add NT here.
__global__ __launch_bounds__(256) void zero_adj_kernel(float* __restrict__ adj)
{
    const size_t n4 = (size_t)B_SZ * B_SZ / 4;
    f32x4 z = {0.f, 0.f, 0.f, 0.f};
    f32x4* p = (f32x4*)adj;
    for (size_t i = (size_t)blockIdx.x * 256 + threadIdx.x; i < n4;
         i += (size_t)gridDim.x * 256)
        p[i] = z;
}

// Wave-per-row preproc: 2048 blocks x 4 waves; wave w handles row blockIdx*4+w.
// conv 2x2/s2 + bias -> 4x4 unitary -> qf (LDS, fp32), row norm -> qn fp8 e4m3.
// qn is K-PLANE-BLOCKED: qn[kt][row][64 B] (13 planes of 512 KB).
__global__ __launch_bounds__(256) void preproc_kernel(
    const float* __restrict__ x, const float* __restrict__ conv_w,
    const float* __restrict__ conv_b, const float* __restrict__ unitary,
    const float* __restrict__ lin_w, const float* __restrict__ lin_b,
    float* __restrict__ log_probs, uchar_t* __restrict__ qn)
{
    __shared__ float xr[4][784];
    __shared__ float qf[4][784];

    const int t = threadIdx.x, lane = t & 63, wave = t >> 6;
    const int b = blockIdx.x * 4 + wave;
    float* xw = xr[wave];
    float* qw = qf[wave];

    const float4* xsrc = (const float4*)(x + (size_t)b * 784);
    #pragma unroll
    for (int i = lane; i < 196; i += 64) ((float4*)xw)[i] = xsrc[i];
    __syncthreads();

    float sumsq = 0.f;
    for (int g = lane; g < 196; g += 64) {
        const int c = g / 49, p = g % 49;
        const float w00 = conv_w[c*4+0], w01 = conv_w[c*4+1];
        const float w10 = conv_w[c*4+2], w11 = conv_w[c*4+3];
        const float bcv = conv_b[c];
        float feat[4];
        #pragma unroll
        for (int j = 0; j < 4; ++j) {
            const int s = 4*p + j;
            const int h = s / 14, wq = s % 14;
            const float* px = &xw[(2*h)*28 + 2*wq];
            feat[j] = bcv + w00*px[0] + w01*px[1] + w10*px[28] + w11*px[29];
        }
        #pragma unroll
        for (int w = 0; w < 4; ++w) {
            float v = unitary[w*4+0]*feat[0] + unitary[w*4+1]*feat[1]
                    + unitary[w*4+2]*feat[2] + unitary[w*4+3]*feat[3];
            qw[4*g + w] = v;
            sumsq += v * v;
        }
    }
    __syncthreads();

    #pragma unroll
    for (int off = 1; off < 64; off <<= 1) sumsq += __shfl_xor(sumsq, off, 64);
    const float inv = 1.0f / (sqrtf(sumsq) + 1e-12f);

    unsigned int* qbase = (unsigned int*)qn;
    for (int i = lane; i < 208; i += 64) {
        unsigned int o = 0u;
        if (i < 196) {
            const float v0 = qw[4*i+0] * inv, v1 = qw[4*i+1] * inv;
            const float v2 = qw[4*i+2] * inv, v3 = qw[4*i+3] * inv;
            int lo = __builtin_amdgcn_cvt_pk_fp8_f32(v0, v1, 0, 0);
            o = (unsigned int)__builtin_amdgcn_cvt_pk_fp8_f32(v2, v3, lo, 1);
        }
        qbase[(size_t)(i >> 4) * PLANE_U32 + (size_t)b * 16 + (i & 15)] = o;
    }

    float acc[10];
    #pragma unroll
    for (int cl = 0; cl < 10; ++cl) acc[cl] = 0.f;
    for (int k = lane; k < 784; k += 64) {
        const float v = qw[k];
        #pragma unroll
        for (int cl = 0; cl < 10; ++cl) acc[cl] += v * lin_w[cl*784 + k];
    }
    #pragma unroll
    for (int cl = 0; cl < 10; ++cl) {
        #pragma unroll
        for (int off = 1; off < 64; off <<= 1)
            acc[cl] += __shfl_xor(acc[cl], off, 64);
        acc[cl] += lin_b[cl];
    }
    if (lane == 0) {
        float mx = -1e30f;
        #pragma unroll
        for (int cl = 0; cl < 10; ++cl) mx = fmaxf(mx, acc[cl]);
        float se = 0.f;
        #pragma unroll
        for (int cl = 0; cl < 10; ++cl) se += expf(acc[cl] - mx);
        const float lse = mx + logf(se);
        #pragma unroll
        for (int cl = 0; cl < 10; ++cl)
            log_probs[(size_t)b*10 + cl] = acc[cl] - lse;
    }
}

// R16: sparse 256x256 gram, 2-BUFFER LDS (64 KB) -> 2 blocks/CU (16 waves/CU,
// 4 waves/SIMD; VGPR 128 -> 16 waves/CU fits, m69). R10 direct counters:
// 1-block/CU 3-buffer version ran 96 us/rep at MfmaUtil 24.8% -- 2 waves/SIMD
// couldn't hide the glds->barrier->ds_read->MFMA chain, and 528 blocks ran as
// ~3 rounds with a 16-block tail. 2 blocks/CU doubles independent waves/SIMD
// and halves the tail quantum. MFMA floor 26 us aggregate.
//
// Depth-1 prefetch, ONE s_barrier per kt:
//   top of kt: only S(kt)'s 4 glds outstanding -> vmcnt(0); s_barrier =>
//   tile kt in LDS AND all waves' kt-1 reads done => buffer p^1 is dead;
//   STAGE(kt+1) -> p^1 issued right after, lands during the 32-MFMA phase.
// Epilogue: sparse 1-fixups only (zeros pre-written by zero_adj_kernel).
//
// LDS per 16-row block rb (1 KB): [chunk 0..3][row 0..15][16 B]; glds lane
// map row=lane&15, chunk=lane>>4 matches dest base+lane*16 (linear; plane-
// blocked source is 16 rows x 64 B contiguous). Fragment (32x32x16): lane l,
// kstep s: addr rb*1024 + s*256 + (r&15)*16 + (l>>5)*8.
// C/D: col = lane&31, row = (reg&3) + 8*(reg>>2) + 4*(lane>>5).
__global__ __launch_bounds__(512, 4) void gram_kernel(
    const uchar_t* __restrict__ qn, float* __restrict__ adj)
{
    // XCD-bijective swizzle: 528 = 8 * 66.
    const int t0 = blockIdx.x;
    int tl = (t0 & 7) * 66 + (t0 >> 3);
    int br = (int)((65.0 - sqrt(4225.0 - 8.0 * (double)tl)) * 0.5);
    while ((br + 1) * (65 - (br + 1)) / 2 <= tl) ++br;
    while (br * (65 - br) / 2 > tl) --br;
    const int bc = br + (tl - br * (65 - br) / 2);

    __shared__ uchar_t ldsA[2][16384] __attribute__((aligned(16)));  // 32 KB
    __shared__ uchar_t ldsB[2][16384] __attribute__((aligned(16)));  // 32 KB

    const int t = threadIdx.x;
    const int lane = t & 63, wave = t >> 6;       // 8 waves
    const int wrow = wave >> 1, wcol = wave & 1;  // 4x2 -> 64x128 per wave
    const int l32 = lane & 31, half = lane >> 5;

    const bool offdiag = (br != bc);
    const int br256 = br * 256, bc256 = bc * 256;

    const int srow = lane & 15, sck = (lane >> 4) * 16;
    const uchar_t* gA0 = qn + (size_t)(br256 + wave*16       + srow) * 64 + sck;
    const uchar_t* gA1 = qn + (size_t)(br256 + (wave+8)*16   + srow) * 64 + sck;
    const uchar_t* gB0 = qn + (size_t)(bc256 + wave*16       + srow) * 64 + sck;
    const uchar_t* gB1 = qn + (size_t)(bc256 + (wave+8)*16   + srow) * 64 + sck;
    const int ld0 = wave * 1024, ld1 = (wave + 8) * 1024;

    #define STAGE(p, koff) do {                                                            \
        __builtin_amdgcn_global_load_lds(GLOBAL_AS(gA0 + (koff)), LDS_AS(&ldsA[p][ld0]), 16, 0, 0); \
        __builtin_amdgcn_global_load_lds(GLOBAL_AS(gA1 + (koff)), LDS_AS(&ldsA[p][ld1]), 16, 0, 0); \
        __builtin_amdgcn_global_load_lds(GLOBAL_AS(gB0 + (koff)), LDS_AS(&ldsB[p][ld0]), 16, 0, 0); \
        __builtin_amdgcn_global_load_lds(GLOBAL_AS(gB1 + (koff)), LDS_AS(&ldsB[p][ld1]), 16, 0, 0); \
    } while (0)

    int aoff[2], boff[4];
    #pragma unroll
    for (int mi = 0; mi < 2; ++mi) {
        const int r = wrow*64 + mi*32 + l32;
        aoff[mi] = (r >> 4)*1024 + (r & 15)*16 + half*8;
    }
    #pragma unroll
    for (int ni = 0; ni < 4; ++ni) {
        const int c = wcol*128 + ni*32 + l32;
        boff[ni] = (c >> 4)*1024 + (c & 15)*16 + half*8;
    }

    f32x16 acc[2][4] = {};
    STAGE(0, 0);

    #pragma unroll
    for (int kt = 0; kt < N_KT; ++kt) {
        const int p = kt & 1;

        asm volatile("" ::: "memory");
        __builtin_amdgcn_s_waitcnt(0xF70);   // vmcnt(0): S(kt) landed (ours)
        __builtin_amdgcn_s_barrier();        // all waves landed; p^1 is dead
        asm volatile("" ::: "memory");

        if (kt + 1 < N_KT) STAGE(p ^ 1, (size_t)(kt + 1) * PLANE_B);
        asm volatile("" ::: "memory");

        #pragma unroll
        for (int s = 0; s < 4; ++s) {
            long a0 = *(const long*)&ldsA[p][aoff[0] + s*256];
            long a1 = *(const long*)&ldsA[p][aoff[1] + s*256];
            long b0 = *(const long*)&ldsB[p][boff[0] + s*256];
            long b1 = *(const long*)&ldsB[p][boff[1] + s*256];
            long b2 = *(const long*)&ldsB[p][boff[2] + s*256];
            long b3 = *(const long*)&ldsB[p][boff[3] + s*256];
            acc[0][0] = __builtin_amdgcn_mfma_f32_32x32x16_fp8_fp8(a0, b0, acc[0][0], 0, 0, 0);
            acc[1][0] = __builtin_amdgcn_mfma_f32_32x32x16_fp8_fp8(a1, b0, acc[1][0], 0, 0, 0);
            acc[0][1] = __builtin_amdgcn_mfma_f32_32x32x16_fp8_fp8(a0, b1, acc[0][1], 0, 0, 0);
            acc[1][1] = __builtin_amdgcn_mfma_f32_32x32x16_fp8_fp8(a1, b1, acc[1][1], 0, 0, 0);
            acc[0][2] = __builtin_amdgcn_mfma_f32_32x32x16_fp8_fp8(a0, b2, acc[0][2], 0, 0, 0);
            acc[1][2] = __builtin_amdgcn_mfma_f32_32x32x16_fp8_fp8(a1, b2, acc[1][2], 0, 0, 0);
            acc[0][3] = __builtin_amdgcn_mfma_f32_32x32x16_fp8_fp8(a0, b3, acc[0][3], 0, 0, 0);
            acc[1][3] = __builtin_amdgcn_mfma_f32_32x32x16_fp8_fp8(a1, b3, acc[1][3], 0, 0, 0);
        }
    }
    #undef STAGE

    // Sparse epilogue: zeros pre-written by zero_adj_kernel (stream-ordered).
    // Only store reg-quads containing a 1 (__any guard).
    #pragma unroll
    for (int mi = 0; mi < 2; ++mi) {
        const int rbase = br256 + wrow*64 + mi*32 + 4*half;
        #pragma unroll
        for (int ni = 0; ni < 4; ++ni) {
            const int gc = bc256 + wcol*128 + ni*32 + l32;
            const f32x16 v = acc[mi][ni];
            #pragma unroll
            for (int q = 0; q < 4; ++q) {
                const int gr0 = rbase + 8*q;
                float o[4];
                bool h = false;
                #pragma unroll
                for (int r = 0; r < 4; ++r) {
                    const float val = v[4*q + r];
                    o[r] = (val*val >= THRESH && (gr0 + r) != gc) ? 1.0f : 0.0f;
                    h = h || (o[r] != 0.0f);
                }
                if (__any(h)) {
                    #pragma unroll
                    for (int r = 0; r < 4; ++r)
                        adj[(size_t)(gr0 + r) * B_SZ + gc] = o[r];
                    if (offdiag)
                        *(float4*)&adj[(size_t)gc * B_SZ + gr0] =
                            make_float4(o[0], o[1], o[2], o[3]);
                }
            }
        }
    }
}

extern "C" void kernel_launch(void* const* d_in, const int* in_sizes, int n_in,
                              void* d_out, int out_size, void* d_ws, size_t ws_size,
                              hipStream_t stream) {
    const float* x       = (const float*)d_in[0];
    const float* conv_w  = (const float*)d_in[1];
    const float* conv_b  = (const float*)d_in[2];
    const float* unitary = (const float*)d_in[3];
    const float* lin_w   = (const float*)d_in[4];
    const float* lin_b   = (const float*)d_in[5];

    float* log_probs = (float*)d_out;
    float* adj       = (float*)d_out + (size_t)B_SZ * 10;
    uchar_t* qn      = (uchar_t*)d_ws;   // 13 planes x [8192][64 B] fp8 e4m3

    // Plain-store streaming fill (~35 us), then preproc (qn lands cache-warm),
    // then 2-blocks/CU sparse gram.
    zero_adj_kernel<<<4096, 256, 0, stream>>>(adj);
    preproc_kernel<<<B_SZ / 4, 256, 0, stream>>>(x, conv_w, conv_b, unitary,
                                                 lin_w, lin_b, log_probs, qn);
    gram_kernel<<<528, 512, 0, stream>>>(qn, adj);
}

// Round 12
// 348.952 us; speedup vs baseline: 3.5205x; 2.8471x over previous
//
#include <hip/hip_runtime.h>
#include <hip/hip_bf16.h>

typedef unsigned char uchar_t;
typedef __attribute__((ext_vector_type(4))) float f32x4;

#define B_SZ 8192
#define D_FT 784
#define N_KT 13
#define PLANE_U32 131072   // 8192 rows * 16 uints (64 B) per plane
#define PLANE_B   524288   // plane stride in bytes
#define THRESH 0.9f
#define PRE_BLKS 2048
#define FILL_BLKS 4096

#define GLOBAL_AS(p) ((const __attribute__((address_space(1))) void*)(p))
#define LDS_AS(p)    ((__attribute__((address_space(3))) void*)(p))

// R17 fused init: blocks 0..2047 run preproc; blocks 2048..6143 zero-fill adj
// with PLAIN f32x4 stores (R10/R11 decomposition: plain fill ~35 us; NT 16-B
// stores were 2.5-3x slower on this path -- never NT here). Independent
// outputs (qn/log_probs vs adj) -> safe to co-dispatch; preproc's ~8 us VALU
// work hides inside the fill's HBM write stream.
__global__ __launch_bounds__(256) void init_kernel(
    const float* __restrict__ x, const float* __restrict__ conv_w,
    const float* __restrict__ conv_b, const float* __restrict__ unitary,
    const float* __restrict__ lin_w, const float* __restrict__ lin_b,
    float* __restrict__ log_probs, uchar_t* __restrict__ qn,
    float* __restrict__ adj)
{
    __shared__ float xr[4][784];
    __shared__ float qf[4][784];

    if (blockIdx.x >= PRE_BLKS) {
        // ---- zero-fill part ----
        const size_t n4 = (size_t)B_SZ * B_SZ / 4;
        f32x4 z = {0.f, 0.f, 0.f, 0.f};
        f32x4* p = (f32x4*)adj;
        for (size_t i = (size_t)(blockIdx.x - PRE_BLKS) * 256 + threadIdx.x;
             i < n4; i += (size_t)FILL_BLKS * 256)
            p[i] = z;
        return;
    }

    // ---- preproc part: wave-per-row, conv 2x2/s2 + unitary -> qf; row-norm
    // -> qn fp8 e4m3, K-plane-blocked qn[kt][row][64 B]; logits+log_softmax.
    const int t = threadIdx.x, lane = t & 63, wave = t >> 6;
    const int b = blockIdx.x * 4 + wave;
    float* xw = xr[wave];
    float* qw = qf[wave];

    const float4* xsrc = (const float4*)(x + (size_t)b * 784);
    #pragma unroll
    for (int i = lane; i < 196; i += 64) ((float4*)xw)[i] = xsrc[i];
    __syncthreads();

    float sumsq = 0.f;
    for (int g = lane; g < 196; g += 64) {
        const int c = g / 49, p = g % 49;
        const float w00 = conv_w[c*4+0], w01 = conv_w[c*4+1];
        const float w10 = conv_w[c*4+2], w11 = conv_w[c*4+3];
        const float bcv = conv_b[c];
        float feat[4];
        #pragma unroll
        for (int j = 0; j < 4; ++j) {
            const int s = 4*p + j;
            const int h = s / 14, wq = s % 14;
            const float* px = &xw[(2*h)*28 + 2*wq];
            feat[j] = bcv + w00*px[0] + w01*px[1] + w10*px[28] + w11*px[29];
        }
        #pragma unroll
        for (int w = 0; w < 4; ++w) {
            float v = unitary[w*4+0]*feat[0] + unitary[w*4+1]*feat[1]
                    + unitary[w*4+2]*feat[2] + unitary[w*4+3]*feat[3];
            qw[4*g + w] = v;
            sumsq += v * v;
        }
    }
    __syncthreads();

    #pragma unroll
    for (int off = 1; off < 64; off <<= 1) sumsq += __shfl_xor(sumsq, off, 64);
    const float inv = 1.0f / (sqrtf(sumsq) + 1e-12f);

    unsigned int* qbase = (unsigned int*)qn;
    for (int i = lane; i < 208; i += 64) {
        unsigned int o = 0u;
        if (i < 196) {
            const float v0 = qw[4*i+0] * inv, v1 = qw[4*i+1] * inv;
            const float v2 = qw[4*i+2] * inv, v3 = qw[4*i+3] * inv;
            int lo = __builtin_amdgcn_cvt_pk_fp8_f32(v0, v1, 0, 0);
            o = (unsigned int)__builtin_amdgcn_cvt_pk_fp8_f32(v2, v3, lo, 1);
        }
        qbase[(size_t)(i >> 4) * PLANE_U32 + (size_t)b * 16 + (i & 15)] = o;
    }

    float acc[10];
    #pragma unroll
    for (int cl = 0; cl < 10; ++cl) acc[cl] = 0.f;
    for (int k = lane; k < 784; k += 64) {
        const float v = qw[k];
        #pragma unroll
        for (int cl = 0; cl < 10; ++cl) acc[cl] += v * lin_w[cl*784 + k];
    }
    #pragma unroll
    for (int cl = 0; cl < 10; ++cl) {
        #pragma unroll
        for (int off = 1; off < 64; off <<= 1)
            acc[cl] += __shfl_xor(acc[cl], off, 64);
        acc[cl] += lin_b[cl];
    }
    if (lane == 0) {
        float mx = -1e30f;
        #pragma unroll
        for (int cl = 0; cl < 10; ++cl) mx = fmaxf(mx, acc[cl]);
        float se = 0.f;
        #pragma unroll
        for (int cl = 0; cl < 10; ++cl) se += expf(acc[cl] - mx);
        const float lse = mx + logf(se);
        #pragma unroll
        for (int cl = 0; cl < 10; ++cl)
            log_probs[(size_t)b*10 + cl] = acc[cl] - lse;
    }
}

// R17 gram: SPARSE 128x128 tile, 4 waves (2x2 of 64x64), mfma_16x16x32_fp8,
// acc = 4x4 f32x4 = 64 regs -> total ~115 <= 128 cap of launch_bounds(256,4)
// => 4 waves/SIMD = 4 blocks/CU (LDS 32 KB, 4x fits). R11's lesson: occupancy
// x accumulator trade through the 512-reg file -- 256^2 tile CANNOT exceed
// 2 waves/SIMD (acc alone = 128 regs; (512,4) spilled acc to scratch: VGPR=64,
// 2.6 GB scratch traffic, MfmaUtil 3.3%). R10 measured 2-waves/SIMD sparse
// gram at 96 us / MfmaUtil 24.8% -- latency-exposed, not traffic-bound
// (HBM 13%). 4 independent blocks/CU at staggered phases hide it.
//
// Depth-1 prefetch, ONE s_barrier per kt: top of kt only S(kt)'s 4 glds
// outstanding -> vmcnt(0); barrier => tile kt in LDS AND buffer p^1 dead;
// STAGE(kt+1)->p^1 lands during the 32-MFMA phase.
//
// LDS per 16-row block rb (1 KB): [chunk 0..3][row 0..15][16 B]; glds lane
// map row=lane&15, chunk=lane>>4 = dest base+lane*16 (linear; plane-blocked
// source = 16 rows x 64 B contiguous). Fragment (16x16x32 fp8): k-byte =
// s*32 + quad*8 -> fo = (2s+(quad>>1))*256 + l16*16 + (quad&1)*8 (R0-proven).
// C/D: row = quad*4 + reg, col = l16.
__global__ __launch_bounds__(256, 4) void gram_kernel(
    const uchar_t* __restrict__ qn, float* __restrict__ adj)
{
    // XCD-bijective swizzle: 2080 = 8 * 260; same-XCD blocks share br.
    const int t0 = blockIdx.x;
    int tl = (t0 & 7) * 260 + (t0 >> 3);
    int br = (int)((129.0 - sqrt(16641.0 - 8.0 * (double)tl)) * 0.5);
    while ((br + 1) * (129 - (br + 1)) / 2 <= tl) ++br;
    while (br * (129 - br) / 2 > tl) --br;
    const int bc = br + (tl - br * (129 - br) / 2);

    __shared__ uchar_t ldsA[2][8192] __attribute__((aligned(16)));  // 16 KB
    __shared__ uchar_t ldsB[2][8192] __attribute__((aligned(16)));  // 16 KB

    const int t = threadIdx.x;
    const int lane = t & 63, wave = t >> 6;
    const int wr = wave >> 1, wc = wave & 1;
    const int quad = lane >> 4, l16 = lane & 15;

    const bool offdiag = (br != bc);
    const int br128 = br * 128, bc128 = bc * 128;

    // staging: wave w stages row-blocks {w, w+4} of A and B (4 glds/kt);
    // plane-blocked: 16 rows x 64 B contiguous per glds.
    const int srow = lane & 15, sck = (lane >> 4) * 16;
    const uchar_t* gA0 = qn + (size_t)(br128 + wave*16     + srow) * 64 + sck;
    const uchar_t* gA1 = qn + (size_t)(br128 + (wave+4)*16 + srow) * 64 + sck;
    const uchar_t* gB0 = qn + (size_t)(bc128 + wave*16     + srow) * 64 + sck;
    const uchar_t* gB1 = qn + (size_t)(bc128 + (wave+4)*16 + srow) * 64 + sck;
    const int ld0 = wave * 1024, ld1 = (wave + 4) * 1024;

    #define STAGE(p, koff) do {                                                            \
        __builtin_amdgcn_global_load_lds(GLOBAL_AS(gA0 + (koff)), LDS_AS(&ldsA[p][ld0]), 16, 0, 0); \
        __builtin_amdgcn_global_load_lds(GLOBAL_AS(gA1 + (koff)), LDS_AS(&ldsA[p][ld1]), 16, 0, 0); \
        __builtin_amdgcn_global_load_lds(GLOBAL_AS(gB0 + (koff)), LDS_AS(&ldsB[p][ld0]), 16, 0, 0); \
        __builtin_amdgcn_global_load_lds(GLOBAL_AS(gB1 + (koff)), LDS_AS(&ldsB[p][ld1]), 16, 0, 0); \
    } while (0)

    f32x4 acc[4][4] = {};
    STAGE(0, 0);

    #pragma unroll
    for (int kt = 0; kt < N_KT; ++kt) {
        const int p = kt & 1;

        asm volatile("" ::: "memory");
        __builtin_amdgcn_s_waitcnt(0xF70);   // vmcnt(0): S(kt) landed (ours)
        __builtin_amdgcn_s_barrier();        // all waves landed; p^1 is dead
        asm volatile("" ::: "memory");

        if (kt + 1 < N_KT) STAGE(p ^ 1, (size_t)(kt + 1) * PLANE_B);
        asm volatile("" ::: "memory");

        #pragma unroll
        for (int s = 0; s < 2; ++s) {
            const int fo = (2*s + (quad >> 1))*256 + l16*16 + (quad & 1)*8;
            long bfr[4];
            #pragma unroll
            for (int ni = 0; ni < 4; ++ni)
                bfr[ni] = *(const long*)&ldsB[p][(wc*4 + ni)*1024 + fo];
            #pragma unroll
            for (int mi = 0; mi < 4; ++mi) {
                const long af = *(const long*)&ldsA[p][(wr*4 + mi)*1024 + fo];
                #pragma unroll
                for (int ni = 0; ni < 4; ++ni)
                    acc[mi][ni] = __builtin_amdgcn_mfma_f32_16x16x32_fp8_fp8(
                        af, bfr[ni], acc[mi][ni], 0, 0, 0);
            }
        }
    }
    #undef STAGE

    // Sparse epilogue: zeros pre-written by init_kernel (stream-ordered).
    // Only store 4-row quads containing a 1 (__any guard).
    #pragma unroll
    for (int mi = 0; mi < 4; ++mi) {
        const int gr0 = br128 + wr*64 + mi*16 + quad*4;
        #pragma unroll
        for (int ni = 0; ni < 4; ++ni) {
            const int gc = bc128 + wc*64 + ni*16 + l16;
            const f32x4 v = acc[mi][ni];
            float o[4];
            bool h = false;
            #pragma unroll
            for (int r = 0; r < 4; ++r) {
                o[r] = (v[r]*v[r] >= THRESH && (gr0 + r) != gc) ? 1.0f : 0.0f;
                h = h || (o[r] != 0.0f);
            }
            if (__any(h)) {
                #pragma unroll
                for (int r = 0; r < 4; ++r)
                    adj[(size_t)(gr0 + r) * B_SZ + gc] = o[r];
                if (offdiag)
                    *(float4*)&adj[(size_t)gc * B_SZ + gr0] =
                        make_float4(o[0], o[1], o[2], o[3]);
            }
        }
    }
}

extern "C" void kernel_launch(void* const* d_in, const int* in_sizes, int n_in,
                              void* d_out, int out_size, void* d_ws, size_t ws_size,
                              hipStream_t stream) {
    const float* x       = (const float*)d_in[0];
    const float* conv_w  = (const float*)d_in[1];
    const float* conv_b  = (const float*)d_in[2];
    const float* unitary = (const float*)d_in[3];
    const float* lin_w   = (const float*)d_in[4];
    const float* lin_b   = (const float*)d_in[5];

    float* log_probs = (float*)d_out;
    float* adj       = (float*)d_out + (size_t)B_SZ * 10;
    uchar_t* qn      = (uchar_t*)d_ws;   // 13 planes x [8192][64 B] fp8 e4m3

    // Fused preproc + plain-store zero-fill (independent outputs overlap),
    // then 4-blocks/CU sparse gram.
    init_kernel<<<PRE_BLKS + FILL_BLKS, 256, 0, stream>>>(
        x, conv_w, conv_b, unitary, lin_w, lin_b, log_probs, qn, adj);
    gram_kernel<<<2080, 256, 0, stream>>>(qn, adj);
}